// Round 11
// baseline (4639.248 us; speedup 1.0000x reference)
//
#include <hip/hip_runtime.h>

typedef unsigned short u16;
typedef __attribute__((ext_vector_type(8))) short short8;   // 8 bf16 = 4 VGPRs (MFMA A/B frag)
typedef __attribute__((ext_vector_type(4))) float f32x4;    // MFMA C/D frag

#define N 1024
#define NSQ (1024 * 1024)
#define NITER 30
#define RBLK 256   /* blocks for chain-free reductions */
#define NBLK 256   /* mega-kernel grid: 1 block/CU (128 KB LDS), capacity co-resident */

__device__ __forceinline__ float b2f(u16 u) {
  union { unsigned int i; float f; } v;
  v.i = ((unsigned int)u) << 16;
  return v.f;
}

__device__ __forceinline__ u16 f2b(float f) {
  union { float f; unsigned int i; } v;
  v.f = f;
  return (u16)((v.i + 0x7fffu + ((v.i >> 16) & 1u)) >> 16);
}

// ---- input dtype detection -------------------------------------------------
__global__ void k_flag(const u16* a, float* flag) {
  if (threadIdx.x == 0 && blockIdx.x == 0) {
    int cnt = 0;
    for (int i = 0; i < 256; ++i) {
      const u16 u = a[2 * i];
      const int e = (u >> 7) & 0xFF;
      if (e >= 100 && e <= 132) ++cnt;
    }
    *flag = (cnt >= 128) ? 1.0f : 0.0f;
  }
}

__global__ void k_sentinel(void* out, const float* flag) {
  if (threadIdx.x == 0 && blockIdx.x == 0) {
    if (*flag > 0.5f) ((u16*)out)[0] = f2b(1000.0f);
    else              ((float*)out)[0] = 1000.0f;
  }
}

__global__ void k_cvt2(const void* a, float* o, const float* flag, int n) {
  const int i = blockIdx.x * 256 + threadIdx.x;
  if (i < n) {
    if (*flag > 0.5f) o[i] = b2f(((const u16*)a)[i]);
    else              o[i] = ((const float*)a)[i];
  }
}

// ---- fp32 -> bf16 (hi, lo) split helpers -----------------------------------
__global__ void k_split(const float* x, u16* h, u16* l) {
  const int i = blockIdx.x * 256 + threadIdx.x;
  const float v = x[i];
  const u16 hi = f2b(v);
  h[i] = hi;
  l[i] = f2b(v - b2f(hi));
}

// T = A^T, split to bf16 hi/lo.  grid (32,32), block (32,8)
__global__ void k_tsplit(const float* A, u16* Th, u16* Tl) {
  __shared__ float s[32][33];
  const int bx = blockIdx.x, by = blockIdx.y;
  const int tx = threadIdx.x, ty = threadIdx.y;
  for (int p = 0; p < 4; ++p)
    s[ty + p * 8][tx] = A[(by * 32 + ty + p * 8) * N + bx * 32 + tx];
  __syncthreads();
  for (int p = 0; p < 4; ++p) {
    const int rT = bx * 32 + ty + p * 8;
    const int cT = by * 32 + tx;
    const float v = s[tx][ty + p * 8];   // = A[cT][rT]
    const u16 hi = f2b(v);
    Th[rT * N + cT] = hi;
    Tl[rT * N + cT] = f2b(v - b2f(hi));
  }
}

__global__ void k_fillsplit(u16* h, u16* l, float v) {
  const int i = blockIdx.x * 256 + threadIdx.x;
  const u16 hi = f2b(v);
  h[i] = hi;
  l[i] = f2b(v - b2f(hi));
}

// ---- split-fp32 NT GEMM via bf16 MFMA --------------------------------------
// C[m][n] = sum_p sum_k P_p[m][k] * Q_p[n][k]   (C = sum_p P_p * Q_p^T)
// hi*hi + hi*lo + lo*hi with fp32 MFMA accumulation (~2^-17 rel error).
struct NTJob {
  const u16* ph[2]; const u16* pl[2];
  const u16* qh[2]; const u16* ql[2];
  float* c; u16* ch; u16* cl;
  int npairs; int wantc; int wantsplit;
};
struct NTBatch { NTJob j[4]; };

#define GLDS(g, l) __builtin_amdgcn_global_load_lds(                         \
    (const __attribute__((address_space(1))) void*)(g),                      \
    (__attribute__((address_space(3))) void*)(l), 16, 0, 0)

// R6-exact GEMM tile body (best measured: 2130 us total), factored into a
// device function so the mega-kernel and the standalone epilogue kernels
// share it. 128xBN tile (BN=128/64), BK=64, 4 waves as 2x2 (per-wave
// 64 x BN/2), double-buffered LDS, 2-barrier counted-vmcnt skeleton:
// next step's GLDS issued BEFORE the wait; wave w stages matrix w
// (0:Ph 1:Pl 2:Qh 3:Ql; 16 GLDS for A mats, BN/8 for B mats; waits
// vmcnt(16)/vmcnt(8)). Rows are 128 B (64 u16); 16B chunks XOR-swizzled
// chunk ^= (row&7) on both the pre-swizzled global source (linear GLDS
// dest) and the ds_read_b128 index -> conflict-free (verified 0).
// LDS layout per buffer p: [Ah | Al | Bh | Bl] at sh + p*BUF.
template <int BN>
__device__ __forceinline__ void nt_tile(const NTJob& job, int by, int bx, u16* sh) {
  constexpr int NT_ = BN / 32;
  constexpr int SZB = BN * 64;            // u16 per B matrix
  constexpr int BUF = 2 * 8192 + 2 * SZB; // u16 per double-buffer half
  const int tid = threadIdx.x;
  const int w = tid >> 6, lane = tid & 63;
  const int m0 = by * 128, n0 = bx * BN;

  const int srow = lane >> 3;             // 0..7: row within an 8-row GLDS group
  const int lchk = (lane & 7) ^ srow;     // pre-swizzled source chunk
  const long lane_off = (long)((w < 2 ? m0 : n0) + srow) * 2048 + (long)lchk * 16;
  const u16* src0 = (w == 0) ? job.ph[0] : (w == 1) ? job.pl[0]
                  : (w == 2) ? job.qh[0] : job.ql[0];
  const u16* src1 = (w == 0) ? job.ph[1] : (w == 1) ? job.pl[1]
                  : (w == 2) ? job.qh[1] : job.ql[1];
  const int moff = (w == 0) ? 0 : (w == 1) ? 8192 : (w == 2) ? 16384 : 16384 + SZB;
  const int nch = (w < 2) ? 16 : (BN / 8);

  // fragment read indices: chunk = (kh*4+g) ^ (row&7); kh flips idx bit 5.
  const int r0 = lane & 15, g = lane >> 4;
  const int wm = (w & 1) * 64, wn = (w >> 1) * (BN / 2);
  int idxA[4], idxB[NT_];
#pragma unroll
  for (int i = 0; i < 4; ++i) {
    const int row = wm + i * 16 + r0;
    idxA[i] = row * 64 + ((g ^ (row & 7)) << 3);
  }
#pragma unroll
  for (int i = 0; i < NT_; ++i) {
    const int row = wn + i * 16 + r0;
    idxB[i] = row * 64 + ((g ^ (row & 7)) << 3);
  }

  f32x4 acc[4][NT_];
#pragma unroll
  for (int mt = 0; mt < 4; ++mt)
#pragma unroll
    for (int nt = 0; nt < NT_; ++nt)
      acc[mt][nt] = (f32x4){0.0f, 0.0f, 0.0f, 0.0f};

  const int nsteps = job.npairs * 16;

  auto issue = [&](int s, int p) {
    const char* src = (const char*)((s & 16) ? src1 : src0) + lane_off
                    + (long)(s & 15) * 128;
    u16* dst = sh + p * BUF + moff;
#pragma unroll
    for (int j = 0; j < 16; ++j)
      if (j < nch) GLDS(src + (long)j * 16384, dst + j * 512);
  };

  issue(0, 0);
  for (int s = 0; s < nsteps; ++s) {
    const int p = s & 1;
    if (s + 1 < nsteps) {
      issue(s + 1, p ^ 1);                                  // prefetch in flight
      if (w < 2 || BN == 128)
        asm volatile("s_waitcnt vmcnt(16)" ::: "memory");   // buf p landed
      else
        asm volatile("s_waitcnt vmcnt(8)" ::: "memory");
    } else {
      asm volatile("s_waitcnt vmcnt(0)" ::: "memory");
    }
    __builtin_amdgcn_s_barrier();
    asm volatile("" ::: "memory");
    const u16* Ahf = sh + p * BUF;
    const u16* Alf = Ahf + 8192;
    const u16* Bhf = Ahf + 16384;
    const u16* Blf = Ahf + 16384 + SZB;
#pragma unroll
    for (int kh = 0; kh < 2; ++kh) {
      const int kx = kh * 32;
      short8 ah[4], al[4];
#pragma unroll
      for (int mt = 0; mt < 4; ++mt) {
        ah[mt] = *(const short8*)(Ahf + (idxA[mt] ^ kx));
        al[mt] = *(const short8*)(Alf + (idxA[mt] ^ kx));
      }
#pragma unroll
      for (int nt = 0; nt < NT_; ++nt) {
        const short8 bh = *(const short8*)(Bhf + (idxB[nt] ^ kx));
        const short8 bl = *(const short8*)(Blf + (idxB[nt] ^ kx));
#pragma unroll
        for (int mt = 0; mt < 4; ++mt) {
          acc[mt][nt] = __builtin_amdgcn_mfma_f32_16x16x32_bf16(ah[mt], bh, acc[mt][nt], 0, 0, 0);
          acc[mt][nt] = __builtin_amdgcn_mfma_f32_16x16x32_bf16(ah[mt], bl, acc[mt][nt], 0, 0, 0);
          acc[mt][nt] = __builtin_amdgcn_mfma_f32_16x16x32_bf16(al[mt], bh, acc[mt][nt], 0, 0, 0);
        }
      }
    }
    asm volatile("" ::: "memory");
    __builtin_amdgcn_s_barrier();   // all waves done reading buf p
  }

  // C/D layout (m89-verified): col = lane&15, row = (lane>>4)*4 + reg
#pragma unroll
  for (int mt = 0; mt < 4; ++mt) {
    const int crw = m0 + wm + mt * 16 + g * 4;
#pragma unroll
    for (int nt = 0; nt < NT_; ++nt) {
      const int ccol = n0 + wn + nt * 16 + r0;
#pragma unroll
      for (int jj = 0; jj < 4; ++jj) {
        const float v = acc[mt][nt][jj];
        const int o = (crw + jj) * N + ccol;
        if (job.wantc) job.c[o] = v;
        if (job.wantsplit) {
          const u16 hi = f2b(v);
          job.ch[o] = hi;
          job.cl[o] = f2b(v - b2f(hi));
        }
      }
    }
  }
}

// standalone wrapper (epilogue launches): same grid decode + XCD swizzle as R6
template <int BN>
__global__ __launch_bounds__(256) void k_nt(NTBatch batch) {
  __shared__ u16 sh[2 * (2 * 8192 + 2 * BN * 64)];
  constexpr int GX = (BN == 128) ? 8 : 16;
  constexpr int PERZ = 8 * GX;
  const int nwg = PERZ * gridDim.z;
  const int d = blockIdx.x + GX * (blockIdx.y + 8 * blockIdx.z);
  const int lin = (d & 7) * (nwg >> 3) + (d >> 3);   // XCD-chunked, bijective
  const int bz = lin / PERZ;
  const int rem = lin % PERZ;
  nt_tile<BN>(batch.j[bz], rem / GX, rem % GX, sh);
}

// ---- device-scope grid barrier (capacity co-resident: 256 blk, 1/CU) -------
// Agent-scope acq/rel atomics + threadfence emit the sc1 L2 writeback/
// invalidate needed for cross-XCD data visibility (guide G16). Sense via a
// monotonic generation counter; count self-resets -> safe across graph
// replays (bar zeroed once per kernel_launch by k_bzero).
__device__ __forceinline__ void gridbar(unsigned* bar) {
  __syncthreads();
  if (threadIdx.x == 0) {
    __threadfence();
    const unsigned gen = __hip_atomic_load(bar + 1, __ATOMIC_RELAXED,
                                           __HIP_MEMORY_SCOPE_AGENT);
    if (__hip_atomic_fetch_add(bar, 1u, __ATOMIC_ACQ_REL,
                               __HIP_MEMORY_SCOPE_AGENT) == NBLK - 1) {
      __hip_atomic_store(bar, 0u, __ATOMIC_RELAXED, __HIP_MEMORY_SCOPE_AGENT);
      __hip_atomic_fetch_add(bar + 1, 1u, __ATOMIC_RELEASE,
                             __HIP_MEMORY_SCOPE_AGENT);
    } else {
      while (__hip_atomic_load(bar + 1, __ATOMIC_ACQUIRE,
                               __HIP_MEMORY_SCOPE_AGENT) == gen)
        __builtin_amdgcn_s_sleep(2);
    }
    __threadfence();
  }
  __syncthreads();
}

__global__ void k_bzero(unsigned* bar) {
  if (threadIdx.x < 2 && blockIdx.x == 0) bar[threadIdx.x] = 0;
}

// ---- mega-kernel: all 30 power iterations in ONE launch ---------------------
// Replaces 60 dependent kernel boundaries (~5-10 us each: drain+ramp+flush)
// with 60 grid barriers (~2-4 us). Phase shapes are R6-exact: phase1 =
// s1 (128x128, 4 jobs, 256 tiles), phase2 = s2 (128x64 dual-pair, 2 jobs,
// 256 tiles). Both phases need exactly NBLK=256 blocks.
__global__ __launch_bounds__(256) void k_loop(NTBatch s1, NTBatch s2,
                                              unsigned* bar) {
  __shared__ u16 sh[2 * (2 * 8192 + 2 * 128 * 64)];   // 128 KB
  const int b = blockIdx.x;
  const int lin = (b & 7) * 32 + (b >> 3);            // XCD swizzle, nwg=256
  const int bz1 = lin >> 6, rem1 = lin & 63;          // phase1: PERZ=64, GX=8
  const int by1 = rem1 >> 3, bx1 = rem1 & 7;
  const int bz2 = lin >> 7, rem2 = lin & 127;         // phase2: PERZ=128, GX=16
  const int by2 = rem2 >> 4, bx2 = rem2 & 15;

  for (int it = 0; it < NITER; ++it) {
    nt_tile<128>(s1.j[bz1], by1, bx1, sh);
    gridbar(bar);
    nt_tile<64>(s2.j[bz2], by2, bx2, sh);
    gridbar(bar);
  }
}

// ---- chain-free reductions (no atomic chains; partials to scratch) ----------
__device__ __forceinline__ float dot4(float4 a, float4 b) {
  return a.x * b.x + a.y * b.y + a.z * b.z + a.w * b.w;
}

// rr = <r,r>, rw = <r,w>, lr = <l,r>; r,l reconstructed from bf16 splits.
__global__ void k_dot3(const u16* rh, const u16* rl, const u16* lh, const u16* ll,
                       const float* wv, float* scr) {
  const int tid = threadIdx.x;
  float a0 = 0.0f, a1 = 0.0f, a2 = 0.0f;
  for (int i = blockIdx.x * 256 + tid; i < NSQ / 8; i += gridDim.x * 256) {
    const short8 rhv = ((const short8*)rh)[i];
    const short8 rlv = ((const short8*)rl)[i];
    const short8 lhv = ((const short8*)lh)[i];
    const short8 llv = ((const short8*)ll)[i];
    const float4 w0 = ((const float4*)wv)[2 * i];
    const float4 w1 = ((const float4*)wv)[2 * i + 1];
    float wj[8] = {w0.x, w0.y, w0.z, w0.w, w1.x, w1.y, w1.z, w1.w};
#pragma unroll
    for (int j = 0; j < 8; ++j) {
      const float rv = b2f((u16)rhv[j]) + b2f((u16)rlv[j]);
      const float lv = b2f((u16)lhv[j]) + b2f((u16)llv[j]);
      a0 += rv * rv;
      a1 += rv * wj[j];
      a2 += lv * rv;
    }
  }
#pragma unroll
  for (int off = 32; off > 0; off >>= 1) {
    a0 += __shfl_down(a0, off);
    a1 += __shfl_down(a1, off);
    a2 += __shfl_down(a2, off);
  }
  __shared__ float sp[3][4];
  const int w = tid >> 6, lane = tid & 63;
  if (lane == 0) { sp[0][w] = a0; sp[1][w] = a1; sp[2][w] = a2; }
  __syncthreads();
  if (tid < 3)
    scr[tid * RBLK + blockIdx.x] = sp[tid][0] + sp[tid][1] + sp[tid][2] + sp[tid][3];
}

// all 16 <U_ab, L_cd> partial dots
__global__ void k_dot16(const float* U0, const float* U1, const float* U2, const float* U3,
                        const float* L0, const float* L1, const float* L2, const float* L3,
                        float* scr) {
  const int tid = threadIdx.x;
  float a[16];
#pragma unroll
  for (int u = 0; u < 16; ++u) a[u] = 0.0f;
  for (int i = blockIdx.x * 256 + tid; i < NSQ / 4; i += gridDim.x * 256) {
    const float4 u0 = ((const float4*)U0)[i], u1 = ((const float4*)U1)[i];
    const float4 u2 = ((const float4*)U2)[i], u3 = ((const float4*)U3)[i];
    const float4 l0 = ((const float4*)L0)[i], l1 = ((const float4*)L1)[i];
    const float4 l2 = ((const float4*)L2)[i], l3 = ((const float4*)L3)[i];
    a[0]  += dot4(u0, l0); a[1]  += dot4(u0, l1); a[2]  += dot4(u0, l2); a[3]  += dot4(u0, l3);
    a[4]  += dot4(u1, l0); a[5]  += dot4(u1, l1); a[6]  += dot4(u1, l2); a[7]  += dot4(u1, l3);
    a[8]  += dot4(u2, l0); a[9]  += dot4(u2, l1); a[10] += dot4(u2, l2); a[11] += dot4(u2, l3);
    a[12] += dot4(u3, l0); a[13] += dot4(u3, l1); a[14] += dot4(u3, l2); a[15] += dot4(u3, l3);
  }
#pragma unroll
  for (int off = 32; off > 0; off >>= 1)
#pragma unroll
    for (int u = 0; u < 16; ++u) a[u] += __shfl_down(a[u], off);
  __shared__ float sp[16][4];
  const int w = tid >> 6, lane = tid & 63;
  if (lane == 0) {
#pragma unroll
    for (int u = 0; u < 16; ++u) sp[u][w] = a[u];
  }
  __syncthreads();
  if (tid < 16)
    scr[tid * RBLK + blockIdx.x] = sp[tid][0] + sp[tid][1] + sp[tid][2] + sp[tid][3];
}

// final: slots[399+u] = sum_b scr[u][b], u in 0..18
__global__ void k_dfin(const float* scr, float* slots) {
  __shared__ float red[256];
  const int tid = threadIdx.x;
  for (int u = 0; u < 19; ++u) {
    red[tid] = scr[u * RBLK + tid];
    __syncthreads();
    for (int off = 128; off > 0; off >>= 1) {
      if (tid < off) red[tid] += red[tid + off];
      __syncthreads();
    }
    if (tid == 0) slots[399 + u] = red[0];
    __syncthreads();
  }
}

// Finalize. Unnormalized iterates: eig = <r,Tr>/<r,r>, E0 = sum h*dots/(lr*eig^2).
__global__ void GMPOmodel_6794638262737_kernel(const void* h, const float* slots,
                                               void* out) {
  if (threadIdx.x == 0 && blockIdx.x == 0) {
    const float bf = slots[512];
    const float rr = slots[399];
    const float rw = slots[400];
    const float lr = slots[401];
    const float eig = rw / rr;
    float num = 0.0f;
    for (int u = 0; u < 16; ++u) {
      const float hv = (bf > 0.5f) ? b2f(((const u16*)h)[u]) : ((const float*)h)[u];
      num += hv * slots[402 + u];
    }
    const float e0 = num / (lr * eig * eig);
    if (bf > 0.5f) ((u16*)out)[0] = f2b(e0);
    else           ((float*)out)[0] = e0;
  }
}

// ---- host -------------------------------------------------------------------
static inline NTJob mkjob(const u16* ph0, const u16* pl0, const u16* qh0, const u16* ql0,
                          const u16* ph1, const u16* pl1, const u16* qh1, const u16* ql1,
                          float* c, u16* ch, u16* cl, int npairs, int wantc, int wantsplit) {
  NTJob j;
  j.ph[0] = ph0; j.pl[0] = pl0; j.qh[0] = qh0; j.ql[0] = ql0;
  j.ph[1] = ph1; j.pl[1] = pl1; j.qh[1] = qh1; j.ql[1] = ql1;
  j.c = c; j.ch = ch; j.cl = cl;
  j.npairs = npairs; j.wantc = wantc; j.wantsplit = wantsplit;
  return j;
}

extern "C" void kernel_launch(void* const* d_in, const int* in_sizes, int n_in,
                              void* d_out, int out_size, void* d_ws, size_t ws_size,
                              hipStream_t stream) {
  (void)in_sizes; (void)n_in; (void)out_size; (void)ws_size;
  const void* Ain = d_in[0];
  const void* hin = d_in[1];
  char* ws = (char*)d_ws;
  const size_t MB = 1u << 20;

  // Workspace: 80 MB + ~24 KB (R4-R10-proven region; R3's 97 MB crashed).
  u16* A0h = (u16*)(ws + 0 * MB);   u16* A0l = (u16*)(ws + 2 * MB);
  u16* A1h = (u16*)(ws + 4 * MB);   u16* A1l = (u16*)(ws + 6 * MB);
  u16* T0h = (u16*)(ws + 8 * MB);   u16* T0l = (u16*)(ws + 10 * MB);
  u16* T1h = (u16*)(ws + 12 * MB);  u16* T1l = (u16*)(ws + 14 * MB);
  u16* rh  = (u16*)(ws + 16 * MB);  u16* rl  = (u16*)(ws + 18 * MB);
  u16* lh  = (u16*)(ws + 20 * MB);  u16* ll  = (u16*)(ws + 22 * MB);
  u16* t0rh = (u16*)(ws + 24 * MB); u16* t0rl = (u16*)(ws + 26 * MB);
  u16* t1rh = (u16*)(ws + 28 * MB); u16* t1rl = (u16*)(ws + 30 * MB);
  u16* t0lh = (u16*)(ws + 32 * MB); u16* t0ll = (u16*)(ws + 34 * MB);
  u16* t1lh = (u16*)(ws + 36 * MB); u16* t1ll = (u16*)(ws + 38 * MB);
  // fp32 buffers (4 MB each)
  float* A0f = (float*)(ws + 40 * MB);   // setup fp32 A0 -> epilogue L00
  float* A1f = (float*)(ws + 44 * MB);   // setup fp32 A1 -> epilogue L01
  float* wf  = (float*)(ws + 56 * MB);   // epilogue mv_r(r) -> U00
  float* L10 = (float*)(ws + 60 * MB);
  float* L11 = (float*)(ws + 64 * MB);
  float* U01 = (float*)(ws + 68 * MB);
  float* U10 = (float*)(ws + 72 * MB);
  float* U11 = (float*)(ws + 76 * MB);
  float* slots = (float*)(ws + 80 * MB); // 1024 floats; [512] = dtype flag
  float* scr   = slots + 1024;           // 19*RBLK floats of reduction partials
  unsigned* bar = (unsigned*)(slots + 600);

  k_bzero<<<1, 64, 0, stream>>>(bar);
  k_flag<<<1, 64, 0, stream>>>((const u16*)Ain, slots + 512);
  k_sentinel<<<1, 64, 0, stream>>>(d_out, slots + 512);
  k_cvt2<<<8192, 256, 0, stream>>>(Ain, A0f, slots + 512, 2 * NSQ);  // fills A0f, A1f

  k_split<<<4096, 256, 0, stream>>>(A0f, A0h, A0l);
  k_split<<<4096, 256, 0, stream>>>(A1f, A1h, A1l);
  k_tsplit<<<dim3(32, 32), dim3(32, 8), 0, stream>>>(A0f, T0h, T0l);
  k_tsplit<<<dim3(32, 32), dim3(32, 8), 0, stream>>>(A1f, T1h, T1l);
  k_fillsplit<<<4096, 256, 0, stream>>>(rh, rl, 1.0f / 1024.0f);
  k_fillsplit<<<4096, 256, 0, stream>>>(lh, ll, 1.0f / 1024.0f);

  // r, l stay symmetric -> all GEMMs in NT form. R6-exact loop jobs:
  // Phase1: t0r=A0*r, t1r=A1*r, t0l=A0^T*l, t1l=A1^T*l (split-only out)
  NTBatch s1;
  s1.j[0] = mkjob(A0h, A0l, rh, rl, 0, 0, 0, 0, 0, t0rh, t0rl, 1, 0, 1);
  s1.j[1] = mkjob(A1h, A1l, rh, rl, 0, 0, 0, 0, 0, t1rh, t1rl, 1, 0, 1);
  s1.j[2] = mkjob(T0h, T0l, lh, ll, 0, 0, 0, 0, 0, t0lh, t0ll, 1, 0, 1);
  s1.j[3] = mkjob(T1h, T1l, lh, ll, 0, 0, 0, 0, 0, t1lh, t1ll, 1, 0, 1);
  // Phase2 (dual-pair full-K, split-only out): r' = t0r*A0^T + t1r*A1^T;
  // l' = t0l*A0 + t1l*A1. In-place split overwrite of r/l is safe (phase2
  // never reads them; gridbar separates from phase1's reads).
  NTBatch s2;
  s2.j[0] = mkjob(t0rh, t0rl, A0h, A0l, t1rh, t1rl, A1h, A1l, 0, rh, rl, 2, 0, 1);
  s2.j[1] = mkjob(t0lh, t0ll, T0h, T0l, t1lh, t1ll, T1h, T1l, 0, lh, ll, 2, 0, 1);

  // One launch, 30 iterations, 60 grid barriers instead of 60 boundaries.
  k_loop<<<NBLK, 256, 0, stream>>>(s1, s2, bar);

  // ---- epilogue (R6-exact; unnormalized, E0 homogeneous deg 0 in r, l) ----
  NTBatch e1;
  e1.j[0] = mkjob(A0h, A0l, rh, rl, 0, 0, 0, 0, 0, t0rh, t0rl, 1, 0, 1);
  e1.j[1] = mkjob(A1h, A1l, rh, rl, 0, 0, 0, 0, 0, t1rh, t1rl, 1, 0, 1);
  k_nt<64><<<dim3(16, 8, 2), 256, 0, stream>>>(e1);
  NTBatch e2;
  e2.j[0] = mkjob(t0rh, t0rl, A0h, A0l, t1rh, t1rl, A1h, A1l, wf, 0, 0, 2, 1, 0);
  k_nt<64><<<dim3(16, 8, 1), 256, 0, stream>>>(e2);
  k_dot3<<<RBLK, 256, 0, stream>>>(rh, rl, lh, ll, wf, scr);   // rr, rw, lr

  // UL_a = l*A_a = NT(l, ATa); URT_b = (A_b r)^T = r*A_b^T = NT(r, A_b)
  NTBatch e3;
  e3.j[0] = mkjob(lh, ll, T0h, T0l, 0, 0, 0, 0, 0, t0lh, t0ll, 1, 0, 1);  // UL0
  e3.j[1] = mkjob(lh, ll, T1h, T1l, 0, 0, 0, 0, 0, t1lh, t1ll, 1, 0, 1);  // UL1
  e3.j[2] = mkjob(rh, rl, A0h, A0l, 0, 0, 0, 0, 0, t0rh, t0rl, 1, 0, 1);  // URT0
  e3.j[3] = mkjob(rh, rl, A1h, A1l, 0, 0, 0, 0, 0, t1rh, t1rl, 1, 0, 1);  // URT1
  k_nt<128><<<dim3(8, 8, 4), 256, 0, stream>>>(e3);

  // L_cd = A_c*A_d = NT(A_c, ATd); fp32 only. A0f/A1f consumed -> L00/L01.
  NTBatch e4;
  e4.j[0] = mkjob(A0h, A0l, T0h, T0l, 0, 0, 0, 0, A0f, 0, 0, 1, 1, 0);
  e4.j[1] = mkjob(A0h, A0l, T1h, T1l, 0, 0, 0, 0, A1f, 0, 0, 1, 1, 0);
  e4.j[2] = mkjob(A1h, A1l, T0h, T0l, 0, 0, 0, 0, L10, 0, 0, 1, 1, 0);
  e4.j[3] = mkjob(A1h, A1l, T1h, T1l, 0, 0, 0, 0, L11, 0, 0, 1, 1, 0);
  k_nt<128><<<dim3(8, 8, 4), 256, 0, stream>>>(e4);

  // U_ab = UL_a * UR_b = NT(UL_a, URT_b); wf dead after k_dot3 -> U00.
  NTBatch e5;
  e5.j[0] = mkjob(t0lh, t0ll, t0rh, t0rl, 0, 0, 0, 0, wf,  0, 0, 1, 1, 0);
  e5.j[1] = mkjob(t0lh, t0ll, t1rh, t1rl, 0, 0, 0, 0, U01, 0, 0, 1, 1, 0);
  e5.j[2] = mkjob(t1lh, t1ll, t0rh, t0rl, 0, 0, 0, 0, U10, 0, 0, 1, 1, 0);
  e5.j[3] = mkjob(t1lh, t1ll, t1rh, t1rl, 0, 0, 0, 0, U11, 0, 0, 1, 1, 0);
  k_nt<128><<<dim3(8, 8, 4), 256, 0, stream>>>(e5);

  k_dot16<<<RBLK, 256, 0, stream>>>(wf, U01, U10, U11, A0f, A1f, L10, L11,
                                    scr + 3 * RBLK);
  k_dfin<<<1, 256, 0, stream>>>(scr, slots);

  GMPOmodel_6794638262737_kernel<<<1, 64, 0, stream>>>(hin, slots, d_out);
}

// Round 12
// 1586.515 us; speedup vs baseline: 2.9242x; 2.9242x over previous
//
#include <hip/hip_runtime.h>

typedef unsigned short u16;
typedef __attribute__((ext_vector_type(8))) short short8;   // 8 bf16 = 4 VGPRs (MFMA A/B frag)
typedef __attribute__((ext_vector_type(4))) float f32x4;    // MFMA C/D frag

#define N 1024
#define NSQ (1024 * 1024)
#define NITER_BF 20   /* bf16-only power iterations (self-correcting phase) */
#define NITER_SP 10   /* split-precision polish iterations */
#define RBLK 256      /* blocks for chain-free reductions */

__device__ __forceinline__ float b2f(u16 u) {
  union { unsigned int i; float f; } v;
  v.i = ((unsigned int)u) << 16;
  return v.f;
}

__device__ __forceinline__ u16 f2b(float f) {
  union { float f; unsigned int i; } v;
  v.f = f;
  return (u16)((v.i + 0x7fffu + ((v.i >> 16) & 1u)) >> 16);
}

// ---- input dtype detection -------------------------------------------------
__global__ void k_flag(const u16* a, float* flag) {
  if (threadIdx.x == 0 && blockIdx.x == 0) {
    int cnt = 0;
    for (int i = 0; i < 256; ++i) {
      const u16 u = a[2 * i];
      const int e = (u >> 7) & 0xFF;
      if (e >= 100 && e <= 132) ++cnt;
    }
    *flag = (cnt >= 128) ? 1.0f : 0.0f;
  }
}

__global__ void k_sentinel(void* out, const float* flag) {
  if (threadIdx.x == 0 && blockIdx.x == 0) {
    if (*flag > 0.5f) ((u16*)out)[0] = f2b(1000.0f);
    else              ((float*)out)[0] = 1000.0f;
  }
}

// fused: input -> fp32 workspace AND bf16 hi/lo split (replaces cvt2+2xsplit)
__global__ void k_cvtsplit(const void* a, float* o, u16* A0h, u16* A0l,
                           u16* A1h, u16* A1l, const float* flag) {
  const int i = blockIdx.x * 256 + threadIdx.x;   // < 2*NSQ
  float v;
  if (*flag > 0.5f) v = b2f(((const u16*)a)[i]);
  else              v = ((const float*)a)[i];
  o[i] = v;
  const u16 hi = f2b(v);
  const u16 lo = f2b(v - b2f(hi));
  if (i < NSQ) { A0h[i] = hi; A0l[i] = lo; }
  else         { A1h[i - NSQ] = hi; A1l[i - NSQ] = lo; }
}

// T = A^T, split to bf16 hi/lo.  grid (32,32), block (32,8)
__global__ void k_tsplit(const float* A, u16* Th, u16* Tl) {
  __shared__ float s[32][33];
  const int bx = blockIdx.x, by = blockIdx.y;
  const int tx = threadIdx.x, ty = threadIdx.y;
  for (int p = 0; p < 4; ++p)
    s[ty + p * 8][tx] = A[(by * 32 + ty + p * 8) * N + bx * 32 + tx];
  __syncthreads();
  for (int p = 0; p < 4; ++p) {
    const int rT = bx * 32 + ty + p * 8;
    const int cT = by * 32 + tx;
    const float v = s[tx][ty + p * 8];   // = A[cT][rT]
    const u16 hi = f2b(v);
    Th[rT * N + cT] = hi;
    Tl[rT * N + cT] = f2b(v - b2f(hi));
  }
}

__global__ void k_fillsplit(u16* h, u16* l, float v) {
  const int i = blockIdx.x * 256 + threadIdx.x;
  const u16 hi = f2b(v);
  h[i] = hi;
  l[i] = f2b(v - b2f(hi));
}

// ---- split-fp32 NT GEMM via bf16 MFMA --------------------------------------
// C[m][n] = sum_p sum_k P_p[m][k] * Q_p[n][k]   (C = sum_p P_p * Q_p^T)
// FULL=1: hi*hi + hi*lo + lo*hi, fp32 MFMA accumulate (~2^-17 rel error).
// FULL=0: hi*hi only (bf16 precision; used for the self-correcting phase).
struct NTJob {
  const u16* ph[2]; const u16* pl[2];
  const u16* qh[2]; const u16* ql[2];
  float* c; u16* ch; u16* cl;
  int npairs; int wantc; int wantsplit;
};
struct NTBatch { NTJob j[4]; };

#define GLDS(g, l) __builtin_amdgcn_global_load_lds(                         \
    (const __attribute__((address_space(1))) void*)(g),                      \
    (__attribute__((address_space(3))) void*)(l), 16, 0, 0)

// R6-winning skeleton (2130 us total), unchanged for FULL=1: 128xBN tile
// (BN=128/64), BK=64, 4 waves as 2x2 (per-wave 64 x BN/2), double-buffered
// LDS, 2-barrier counted-vmcnt: next step's GLDS issued BEFORE the wait.
// FULL=1 staging: wave w stages matrix w (0:Ph 1:Pl 2:Qh 3:Ql), waits
// vmcnt(16)/(8). FULL=0 staging: waves 0,1 split Ph's 16 chunks; waves 2,3
// split Qh's BN/8 chunks; waits vmcnt(8)/(4). Rows are 128 B; 16B chunks
// XOR-swizzled chunk^=(row&7) on both the pre-swizzled global source
// (linear GLDS dest) and the ds_read_b128 index -> conflict-free
// (SQ_LDS_BANK_CONFLICT = 0 verified). XCD swizzle (bijective, nwg%8==0).
template <int BN, int FULL>
__global__ __launch_bounds__(256) void k_nt(NTBatch batch) {
  constexpr int NT_ = BN / 32;
  constexpr int SZB = BN * 64;            // u16 per B matrix
  constexpr int BUF = 2 * 8192 + 2 * SZB; // u16 per double-buffer half
  __shared__ u16 sh[2 * BUF];
  constexpr int GX = (BN == 128) ? 8 : 16;
  constexpr int PERZ = 8 * GX;

  const int tid = threadIdx.x;
  const int w = tid >> 6, lane = tid & 63;

  const int nwg = PERZ * gridDim.z;
  const int d = blockIdx.x + GX * (blockIdx.y + 8 * blockIdx.z);
  const int lin = (d & 7) * (nwg >> 3) + (d >> 3);   // XCD-chunked, bijective
  const int bz = lin / PERZ;
  const int rem = lin % PERZ;
  const int by = rem / GX, bx = rem % GX;

  const NTJob job = batch.j[bz];
  const int m0 = by * 128, n0 = bx * BN;

  const int srow = lane >> 3;             // 0..7: row within an 8-row GLDS group
  const int lchk = (lane & 7) ^ srow;     // pre-swizzled source chunk
  const long lane_off = (long)((w < 2 ? m0 : n0) + srow) * 2048 + (long)lchk * 16;

  const u16 *src0, *src1;
  int moff, nch, c0;
  if (FULL) {
    src0 = (w == 0) ? job.ph[0] : (w == 1) ? job.pl[0]
         : (w == 2) ? job.qh[0] : job.ql[0];
    src1 = (w == 0) ? job.ph[1] : (w == 1) ? job.pl[1]
         : (w == 2) ? job.qh[1] : job.ql[1];
    moff = (w == 0) ? 0 : (w == 1) ? 8192 : (w == 2) ? 16384 : 16384 + SZB;
    nch = (w < 2) ? 16 : (BN / 8);
    c0 = 0;
  } else {
    src0 = (w < 2) ? job.ph[0] : job.qh[0];
    src1 = (w < 2) ? job.ph[1] : job.qh[1];
    moff = (w < 2) ? 0 : 16384;
    nch = (w < 2) ? 8 : (BN / 16);
    c0 = (w & 1) * nch;
  }

  // fragment read indices: chunk = (kh*4+g) ^ (row&7); kh flips idx bit 5.
  const int r0 = lane & 15, g = lane >> 4;
  const int wm = (w & 1) * 64, wn = (w >> 1) * (BN / 2);
  int idxA[4], idxB[NT_];
#pragma unroll
  for (int i = 0; i < 4; ++i) {
    const int row = wm + i * 16 + r0;
    idxA[i] = row * 64 + ((g ^ (row & 7)) << 3);
  }
#pragma unroll
  for (int i = 0; i < NT_; ++i) {
    const int row = wn + i * 16 + r0;
    idxB[i] = row * 64 + ((g ^ (row & 7)) << 3);
  }

  f32x4 acc[4][NT_];
#pragma unroll
  for (int mt = 0; mt < 4; ++mt)
#pragma unroll
    for (int nt = 0; nt < NT_; ++nt)
      acc[mt][nt] = (f32x4){0.0f, 0.0f, 0.0f, 0.0f};

  const int nsteps = job.npairs * 16;

  auto issue = [&](int s, int p) {
    const char* src = (const char*)((s & 16) ? src1 : src0) + lane_off
                    + (long)(s & 15) * 128;
    u16* dst = sh + p * BUF + moff;
#pragma unroll
    for (int j = 0; j < 16; ++j)
      if (j < nch) GLDS(src + (long)(c0 + j) * 16384, dst + (c0 + j) * 512);
  };

  issue(0, 0);
  for (int s = 0; s < nsteps; ++s) {
    const int p = s & 1;
    if (s + 1 < nsteps) {
      issue(s + 1, p ^ 1);                                  // prefetch in flight
      if (FULL) {
        if (w < 2 || BN == 128)
          asm volatile("s_waitcnt vmcnt(16)" ::: "memory"); // buf p landed
        else
          asm volatile("s_waitcnt vmcnt(8)" ::: "memory");
      } else {
        if (w < 2 || BN == 128)
          asm volatile("s_waitcnt vmcnt(8)" ::: "memory");
        else
          asm volatile("s_waitcnt vmcnt(4)" ::: "memory");
      }
    } else {
      asm volatile("s_waitcnt vmcnt(0)" ::: "memory");
    }
    __builtin_amdgcn_s_barrier();
    asm volatile("" ::: "memory");
    const u16* Ahf = sh + p * BUF;
    const u16* Alf = Ahf + 8192;
    const u16* Bhf = Ahf + 16384;
    const u16* Blf = Ahf + 16384 + SZB;
#pragma unroll
    for (int kh = 0; kh < 2; ++kh) {
      const int kx = kh * 32;
      short8 ah[4], al[4];
#pragma unroll
      for (int mt = 0; mt < 4; ++mt) {
        ah[mt] = *(const short8*)(Ahf + (idxA[mt] ^ kx));
        if (FULL) al[mt] = *(const short8*)(Alf + (idxA[mt] ^ kx));
      }
#pragma unroll
      for (int nt = 0; nt < NT_; ++nt) {
        const short8 bh = *(const short8*)(Bhf + (idxB[nt] ^ kx));
#pragma unroll
        for (int mt = 0; mt < 4; ++mt)
          acc[mt][nt] = __builtin_amdgcn_mfma_f32_16x16x32_bf16(ah[mt], bh, acc[mt][nt], 0, 0, 0);
        if (FULL) {
          const short8 bl = *(const short8*)(Blf + (idxB[nt] ^ kx));
#pragma unroll
          for (int mt = 0; mt < 4; ++mt) {
            acc[mt][nt] = __builtin_amdgcn_mfma_f32_16x16x32_bf16(ah[mt], bl, acc[mt][nt], 0, 0, 0);
            acc[mt][nt] = __builtin_amdgcn_mfma_f32_16x16x32_bf16(al[mt], bh, acc[mt][nt], 0, 0, 0);
          }
        }
      }
    }
    asm volatile("" ::: "memory");
    __builtin_amdgcn_s_barrier();   // all waves done reading buf p
  }

  // C/D layout (m89-verified): col = lane&15, row = (lane>>4)*4 + reg
#pragma unroll
  for (int mt = 0; mt < 4; ++mt) {
    const int crw = m0 + wm + mt * 16 + g * 4;
#pragma unroll
    for (int nt = 0; nt < NT_; ++nt) {
      const int ccol = n0 + wn + nt * 16 + r0;
#pragma unroll
      for (int jj = 0; jj < 4; ++jj) {
        const float v = acc[mt][nt][jj];
        const int o = (crw + jj) * N + ccol;
        if (job.wantc) job.c[o] = v;
        if (job.wantsplit) {
          const u16 hi = f2b(v);
          job.ch[o] = hi;
          job.cl[o] = f2b(v - b2f(hi));
        }
      }
    }
  }
}

// o = a + b (element-wise)
__global__ void k_comb1(const float* a, const float* b, float* o) {
  const int i = blockIdx.x * 256 + threadIdx.x;
  o[i] = a[i] + b[i];
}

// ---- chain-free reductions (no atomic chains; partials to scratch) ----------
__device__ __forceinline__ float dot4(float4 a, float4 b) {
  return a.x * b.x + a.y * b.y + a.z * b.z + a.w * b.w;
}

// rr = <r,r>, rw = <r,w>, lr = <l,r>; r,l reconstructed from bf16 splits.
__global__ void k_dot3(const u16* rh, const u16* rl, const u16* lh, const u16* ll,
                       const float* wv, float* scr) {
  const int tid = threadIdx.x;
  float a0 = 0.0f, a1 = 0.0f, a2 = 0.0f;
  for (int i = blockIdx.x * 256 + tid; i < NSQ / 8; i += gridDim.x * 256) {
    const short8 rhv = ((const short8*)rh)[i];
    const short8 rlv = ((const short8*)rl)[i];
    const short8 lhv = ((const short8*)lh)[i];
    const short8 llv = ((const short8*)ll)[i];
    const float4 w0 = ((const float4*)wv)[2 * i];
    const float4 w1 = ((const float4*)wv)[2 * i + 1];
    float wj[8] = {w0.x, w0.y, w0.z, w0.w, w1.x, w1.y, w1.z, w1.w};
#pragma unroll
    for (int j = 0; j < 8; ++j) {
      const float rv = b2f((u16)rhv[j]) + b2f((u16)rlv[j]);
      const float lv = b2f((u16)lhv[j]) + b2f((u16)llv[j]);
      a0 += rv * rv;
      a1 += rv * wj[j];
      a2 += lv * rv;
    }
  }
#pragma unroll
  for (int off = 32; off > 0; off >>= 1) {
    a0 += __shfl_down(a0, off);
    a1 += __shfl_down(a1, off);
    a2 += __shfl_down(a2, off);
  }
  __shared__ float sp[3][4];
  const int w = tid >> 6, lane = tid & 63;
  if (lane == 0) { sp[0][w] = a0; sp[1][w] = a1; sp[2][w] = a2; }
  __syncthreads();
  if (tid < 3)
    scr[tid * RBLK + blockIdx.x] = sp[tid][0] + sp[tid][1] + sp[tid][2] + sp[tid][3];
}

// all 16 <U_ab, L_cd> partial dots
__global__ void k_dot16(const float* U0, const float* U1, const float* U2, const float* U3,
                        const float* L0, const float* L1, const float* L2, const float* L3,
                        float* scr) {
  const int tid = threadIdx.x;
  float a[16];
#pragma unroll
  for (int u = 0; u < 16; ++u) a[u] = 0.0f;
  for (int i = blockIdx.x * 256 + tid; i < NSQ / 4; i += gridDim.x * 256) {
    const float4 u0 = ((const float4*)U0)[i], u1 = ((const float4*)U1)[i];
    const float4 u2 = ((const float4*)U2)[i], u3 = ((const float4*)U3)[i];
    const float4 l0 = ((const float4*)L0)[i], l1 = ((const float4*)L1)[i];
    const float4 l2 = ((const float4*)L2)[i], l3 = ((const float4*)L3)[i];
    a[0]  += dot4(u0, l0); a[1]  += dot4(u0, l1); a[2]  += dot4(u0, l2); a[3]  += dot4(u0, l3);
    a[4]  += dot4(u1, l0); a[5]  += dot4(u1, l1); a[6]  += dot4(u1, l2); a[7]  += dot4(u1, l3);
    a[8]  += dot4(u2, l0); a[9]  += dot4(u2, l1); a[10] += dot4(u2, l2); a[11] += dot4(u2, l3);
    a[12] += dot4(u3, l0); a[13] += dot4(u3, l1); a[14] += dot4(u3, l2); a[15] += dot4(u3, l3);
  }
#pragma unroll
  for (int off = 32; off > 0; off >>= 1)
#pragma unroll
    for (int u = 0; u < 16; ++u) a[u] += __shfl_down(a[u], off);
  __shared__ float sp[16][4];
  const int w = tid >> 6, lane = tid & 63;
  if (lane == 0) {
#pragma unroll
    for (int u = 0; u < 16; ++u) sp[u][w] = a[u];
  }
  __syncthreads();
  if (tid < 16)
    scr[tid * RBLK + blockIdx.x] = sp[tid][0] + sp[tid][1] + sp[tid][2] + sp[tid][3];
}

// final: slots[399+u] = sum_b scr[u][b], u in 0..18
__global__ void k_dfin(const float* scr, float* slots) {
  __shared__ float red[256];
  const int tid = threadIdx.x;
  for (int u = 0; u < 19; ++u) {
    red[tid] = scr[u * RBLK + tid];
    __syncthreads();
    for (int off = 128; off > 0; off >>= 1) {
      if (tid < off) red[tid] += red[tid + off];
      __syncthreads();
    }
    if (tid == 0) slots[399 + u] = red[0];
    __syncthreads();
  }
}

// Finalize. Unnormalized iterates: eig = <r,Tr>/<r,r>, E0 = sum h*dots/(lr*eig^2).
__global__ void GMPOmodel_6794638262737_kernel(const void* h, const float* slots,
                                               void* out) {
  if (threadIdx.x == 0 && blockIdx.x == 0) {
    const float bf = slots[512];
    const float rr = slots[399];
    const float rw = slots[400];
    const float lr = slots[401];
    const float eig = rw / rr;
    float num = 0.0f;
    for (int u = 0; u < 16; ++u) {
      const float hv = (bf > 0.5f) ? b2f(((const u16*)h)[u]) : ((const float*)h)[u];
      num += hv * slots[402 + u];
    }
    const float e0 = num / (lr * eig * eig);
    if (bf > 0.5f) ((u16*)out)[0] = f2b(e0);
    else           ((float*)out)[0] = e0;
  }
}

// ---- host -------------------------------------------------------------------
static inline NTJob mkjob(const u16* ph0, const u16* pl0, const u16* qh0, const u16* ql0,
                          const u16* ph1, const u16* pl1, const u16* qh1, const u16* ql1,
                          float* c, u16* ch, u16* cl, int npairs, int wantc, int wantsplit) {
  NTJob j;
  j.ph[0] = ph0; j.pl[0] = pl0; j.qh[0] = qh0; j.ql[0] = ql0;
  j.ph[1] = ph1; j.pl[1] = pl1; j.qh[1] = qh1; j.ql[1] = ql1;
  j.c = c; j.ch = ch; j.cl = cl;
  j.npairs = npairs; j.wantc = wantc; j.wantsplit = wantsplit;
  return j;
}

extern "C" void kernel_launch(void* const* d_in, const int* in_sizes, int n_in,
                              void* d_out, int out_size, void* d_ws, size_t ws_size,
                              hipStream_t stream) {
  (void)in_sizes; (void)n_in; (void)out_size; (void)ws_size;
  const void* Ain = d_in[0];
  const void* hin = d_in[1];
  char* ws = (char*)d_ws;
  const size_t MB = 1u << 20;

  // Workspace: 80 MB + ~24 KB (R4-R11-proven region).
  u16* A0h = (u16*)(ws + 0 * MB);   u16* A0l = (u16*)(ws + 2 * MB);
  u16* A1h = (u16*)(ws + 4 * MB);   u16* A1l = (u16*)(ws + 6 * MB);
  u16* T0h = (u16*)(ws + 8 * MB);   u16* T0l = (u16*)(ws + 10 * MB);
  u16* T1h = (u16*)(ws + 12 * MB);  u16* T1l = (u16*)(ws + 14 * MB);
  u16* rh  = (u16*)(ws + 16 * MB);  u16* rl  = (u16*)(ws + 18 * MB);
  u16* lh  = (u16*)(ws + 20 * MB);  u16* ll  = (u16*)(ws + 22 * MB);
  u16* t0rh = (u16*)(ws + 24 * MB); u16* t0rl = (u16*)(ws + 26 * MB);
  u16* t1rh = (u16*)(ws + 28 * MB); u16* t1rl = (u16*)(ws + 30 * MB);
  u16* t0lh = (u16*)(ws + 32 * MB); u16* t0ll = (u16*)(ws + 34 * MB);
  u16* t1lh = (u16*)(ws + 36 * MB); u16* t1ll = (u16*)(ws + 38 * MB);
  // fp32 buffers (4 MB each)
  float* A0f = (float*)(ws + 40 * MB);   // setup fp32 A0 -> epilogue L00
  float* A1f = (float*)(ws + 44 * MB);   // setup fp32 A1 -> epilogue L01
  float* wf  = (float*)(ws + 56 * MB);   // epilogue mv_r(r) -> U00
  float* L10 = (float*)(ws + 60 * MB);
  float* L11 = (float*)(ws + 64 * MB);
  float* U01 = (float*)(ws + 68 * MB);
  float* U10 = (float*)(ws + 72 * MB);   // also e2 partial 0
  float* U11 = (float*)(ws + 76 * MB);   // also e2 partial 1
  float* slots = (float*)(ws + 80 * MB); // 1024 floats; [512] = dtype flag
  float* scr   = slots + 1024;           // 19*RBLK floats of reduction partials

  k_flag<<<1, 64, 0, stream>>>((const u16*)Ain, slots + 512);
  k_sentinel<<<1, 64, 0, stream>>>(d_out, slots + 512);
  k_cvtsplit<<<8192, 256, 0, stream>>>(Ain, A0f, A0h, A0l, A1h, A1l, slots + 512);
  k_tsplit<<<dim3(32, 32), dim3(32, 8), 0, stream>>>(A0f, T0h, T0l);
  k_tsplit<<<dim3(32, 32), dim3(32, 8), 0, stream>>>(A1f, T1h, T1l);
  k_fillsplit<<<4096, 256, 0, stream>>>(rh, rl, 1.0f / 1024.0f);
  k_fillsplit<<<4096, 256, 0, stream>>>(lh, ll, 1.0f / 1024.0f);

  // r, l stay symmetric -> all GEMMs in NT form. R6-exact loop jobs:
  // Stage 1: t0r=A0*r, t1r=A1*r, t0l=A0^T*l, t1l=A1^T*l (split-only out)
  NTBatch s1;
  s1.j[0] = mkjob(A0h, A0l, rh, rl, 0, 0, 0, 0, 0, t0rh, t0rl, 1, 0, 1);
  s1.j[1] = mkjob(A1h, A1l, rh, rl, 0, 0, 0, 0, 0, t1rh, t1rl, 1, 0, 1);
  s1.j[2] = mkjob(T0h, T0l, lh, ll, 0, 0, 0, 0, 0, t0lh, t0ll, 1, 0, 1);
  s1.j[3] = mkjob(T1h, T1l, lh, ll, 0, 0, 0, 0, 0, t1lh, t1ll, 1, 0, 1);
  // Stage 2 (dual-pair full-K, split-only out): r' = t0r*A0^T + t1r*A1^T;
  // l' = t0l*A0 + t1l*A1. (bf16-phase tiles also write both splits, so the
  // split-precision phase starts from consistent (hi, lo) vectors.)
  NTBatch s2;
  s2.j[0] = mkjob(t0rh, t0rl, A0h, A0l, t1rh, t1rl, A1h, A1l, 0, rh, rl, 2, 0, 1);
  s2.j[1] = mkjob(t0lh, t0ll, T0h, T0l, t1lh, t1ll, T1h, T1l, 0, lh, ll, 2, 0, 1);

  // Phase A: bf16-only power iterations (1 MFMA pass, half staging) --
  // direction errors injected here decay geometrically under phase B.
  for (int it = 0; it < NITER_BF; ++it) {
    k_nt<128, 0><<<dim3(8, 8, 4), 256, 0, stream>>>(s1);
    k_nt<64, 0><<<dim3(16, 8, 2), 256, 0, stream>>>(s2);
  }
  // Phase B: split-precision polish (R6-exact math).
  for (int it = 0; it < NITER_SP; ++it) {
    k_nt<128, 1><<<dim3(8, 8, 4), 256, 0, stream>>>(s1);
    k_nt<64, 1><<<dim3(16, 8, 2), 256, 0, stream>>>(s2);
  }

  // ---- epilogue (R6-exact; unnormalized, E0 homogeneous deg 0 in r, l) ----
  NTBatch e1;
  e1.j[0] = mkjob(A0h, A0l, rh, rl, 0, 0, 0, 0, 0, t0rh, t0rl, 1, 0, 1);
  e1.j[1] = mkjob(A1h, A1l, rh, rl, 0, 0, 0, 0, 0, t1rh, t1rl, 1, 0, 1);
  k_nt<64, 1><<<dim3(16, 8, 2), 256, 0, stream>>>(e1);
  NTBatch e2;
  e2.j[0] = mkjob(t0rh, t0rl, A0h, A0l, 0, 0, 0, 0, U10, 0, 0, 1, 1, 0);
  e2.j[1] = mkjob(t1rh, t1rl, A1h, A1l, 0, 0, 0, 0, U11, 0, 0, 1, 1, 0);
  k_nt<64, 1><<<dim3(16, 8, 2), 256, 0, stream>>>(e2);
  k_comb1<<<4096, 256, 0, stream>>>(U10, U11, wf);
  k_dot3<<<RBLK, 256, 0, stream>>>(rh, rl, lh, ll, wf, scr);   // rr, rw, lr

  // UL_a = l*A_a = NT(l, ATa); URT_b = (A_b r)^T = r*A_b^T = NT(r, A_b)
  NTBatch e3;
  e3.j[0] = mkjob(lh, ll, T0h, T0l, 0, 0, 0, 0, 0, t0lh, t0ll, 1, 0, 1);  // UL0
  e3.j[1] = mkjob(lh, ll, T1h, T1l, 0, 0, 0, 0, 0, t1lh, t1ll, 1, 0, 1);  // UL1
  e3.j[2] = mkjob(rh, rl, A0h, A0l, 0, 0, 0, 0, 0, t0rh, t0rl, 1, 0, 1);  // URT0
  e3.j[3] = mkjob(rh, rl, A1h, A1l, 0, 0, 0, 0, 0, t1rh, t1rl, 1, 0, 1);  // URT1
  k_nt<128, 1><<<dim3(8, 8, 4), 256, 0, stream>>>(e3);

  // L_cd = A_c*A_d = NT(A_c, ATd); fp32 only. A0f/A1f consumed -> L00/L01.
  NTBatch e4;
  e4.j[0] = mkjob(A0h, A0l, T0h, T0l, 0, 0, 0, 0, A0f, 0, 0, 1, 1, 0);
  e4.j[1] = mkjob(A0h, A0l, T1h, T1l, 0, 0, 0, 0, A1f, 0, 0, 1, 1, 0);
  e4.j[2] = mkjob(A1h, A1l, T0h, T0l, 0, 0, 0, 0, L10, 0, 0, 1, 1, 0);
  e4.j[3] = mkjob(A1h, A1l, T1h, T1l, 0, 0, 0, 0, L11, 0, 0, 1, 1, 0);
  k_nt<128, 1><<<dim3(8, 8, 4), 256, 0, stream>>>(e4);

  // U_ab = UL_a * UR_b = NT(UL_a, URT_b); wf dead after k_dot3 -> U00.
  NTBatch e5;
  e5.j[0] = mkjob(t0lh, t0ll, t0rh, t0rl, 0, 0, 0, 0, wf,  0, 0, 1, 1, 0);
  e5.j[1] = mkjob(t0lh, t0ll, t1rh, t1rl, 0, 0, 0, 0, U01, 0, 0, 1, 1, 0);
  e5.j[2] = mkjob(t1lh, t1ll, t0rh, t0rl, 0, 0, 0, 0, U10, 0, 0, 1, 1, 0);
  e5.j[3] = mkjob(t1lh, t1ll, t1rh, t1rl, 0, 0, 0, 0, U11, 0, 0, 1, 1, 0);
  k_nt<128, 1><<<dim3(8, 8, 4), 256, 0, stream>>>(e5);

  k_dot16<<<RBLK, 256, 0, stream>>>(wf, U01, U10, U11, A0f, A1f, L10, L11,
                                    scr + 3 * RBLK);
  k_dfin<<<1, 256, 0, stream>>>(scr, slots);

  GMPOmodel_6794638262737_kernel<<<1, 64, 0, stream>>>(hin, slots, d_out);
}